// Round 6
// baseline (153.496 us; speedup 1.0000x reference)
//
#include <hip/hip_runtime.h>

#define N_NODES 10000
#define D 128
#define N_EDGES 640000
#define NB 128                 // histogram blocks
#define EPB (N_EDGES / NB)     // 5000 edges per block
#define SB 40                  // scan blocks
#define NPSB 250               // nodes per scan block

// ---------------- cast x -> bf16 (so gather working set fits per-XCD L2) -------

__device__ __forceinline__ unsigned short f2bf(float f) {
    union { float f; unsigned int i; } v;
    v.f = f;
    unsigned int b = v.i;
    // round-to-nearest-even (matches hardware bf16 cast for normal values)
    unsigned int rounded = b + 0x7fffu + ((b >> 16) & 1u);
    return (unsigned short)(rounded >> 16);
}

__global__ __launch_bounds__(256) void cast_kernel(const float4* __restrict__ x4,
                                                   ushort4* __restrict__ xh4) {
    int i = blockIdx.x * 256 + threadIdx.x;          // 320000 float4 groups
    if (i < N_NODES * D / 4) {
        float4 v = x4[i];
        ushort4 o;
        o.x = f2bf(v.x);
        o.y = f2bf(v.y);
        o.z = f2bf(v.z);
        o.w = f2bf(v.w);
        xh4[i] = o;
    }
}

// ---------------- CSR build: two-level LDS counting sort ----------------

__global__ __launch_bounds__(1024) void hist_local_kernel(const int* __restrict__ ei,
                                                          unsigned short* __restrict__ lrank,
                                                          unsigned short* __restrict__ cnt,
                                                          unsigned long long* __restrict__ flags) {
    __shared__ int h[N_NODES];
    for (int n = threadIdx.x; n < N_NODES; n += 1024) h[n] = 0;
    if (blockIdx.x == 0 && threadIdx.x < SB) flags[threadIdx.x] = 0ULL;
    __syncthreads();
    const int base = blockIdx.x * EPB;
    for (int e = base + threadIdx.x; e < base + EPB; e += 1024) {
        int d = ei[N_EDGES + e];            // row 1 = dst
        lrank[e] = (unsigned short)atomicAdd(&h[d], 1);
    }
    __syncthreads();
    unsigned short* c = cnt + (size_t)blockIdx.x * N_NODES;
    for (int n = threadIdx.x; n < N_NODES; n += 1024) c[n] = (unsigned short)h[n];
}

__global__ __launch_bounds__(256) void colscan_scan_kernel(unsigned short* __restrict__ cnt,
                                                           int* __restrict__ row_start,
                                                           unsigned long long* __restrict__ flags) {
    const int t = threadIdx.x;
    const int b = blockIdx.x;
    const int n = b * NPSB + t;            // valid for t < NPSB
    __shared__ int sc[256];
    __shared__ int blk_excl_sh;

    int deg = 0;
    if (t < NPSB) {
        int s = 0;
#pragma unroll 8
        for (int j = 0; j < NB; ++j) {
            int idx = j * N_NODES + n;
            int v = cnt[idx];
            cnt[idx] = (unsigned short)s;
            s += v;
        }
        deg = s;
    }
    sc[t] = deg;
    __syncthreads();
    for (int off = 1; off < 256; off <<= 1) {
        int v = (t >= off) ? sc[t - off] : 0;
        __syncthreads();
        sc[t] += v;
        __syncthreads();
    }
    const int total = sc[255];
    const int local_excl = sc[t] - deg;

    if (t == 0) {
        int excl = 0;
        if (b == 0) {
            __hip_atomic_store(&flags[0], (2ULL << 32) | (unsigned)total,
                               __ATOMIC_RELEASE, __HIP_MEMORY_SCOPE_AGENT);
        } else {
            __hip_atomic_store(&flags[b], (1ULL << 32) | (unsigned)total,
                               __ATOMIC_RELEASE, __HIP_MEMORY_SCOPE_AGENT);
            int j = b - 1;
            while (j >= 0) {
                unsigned long long f = __hip_atomic_load(&flags[j], __ATOMIC_ACQUIRE,
                                                         __HIP_MEMORY_SCOPE_AGENT);
                unsigned st = (unsigned)(f >> 32);
                if (st == 0) continue;
                excl += (int)(unsigned)(f & 0xffffffffULL);
                if (st == 2) break;
                --j;
            }
            __hip_atomic_store(&flags[b], (2ULL << 32) | (unsigned)(excl + total),
                               __ATOMIC_RELEASE, __HIP_MEMORY_SCOPE_AGENT);
        }
        blk_excl_sh = excl;
    }
    __syncthreads();
    if (t < NPSB) row_start[n] = blk_excl_sh + local_excl;
    if (b == SB - 1 && t == 0) row_start[N_NODES] = N_EDGES;
}

__global__ __launch_bounds__(256) void scatter_kernel(const int* __restrict__ ei,
                                                      const int* __restrict__ row_start,
                                                      const unsigned short* __restrict__ cnt,
                                                      const unsigned short* __restrict__ lrank,
                                                      unsigned short* __restrict__ csr) {
    int i = blockIdx.x * 256 + threadIdx.x;
    if (i < N_EDGES) {
        int b = i / EPB;
        int s = ei[i];
        int d = ei[N_EDGES + i];
        int pos = row_start[d] + (int)cnt[b * N_NODES + d] + (int)lrank[i];
        csr[pos] = (unsigned short)s;
    }
}

// ---------------- mean aggregation: bf16 gather (L2-resident), fp32 accumulate ----

__device__ __forceinline__ float bf2f(unsigned short u) {
    union { unsigned int i; float f; } v;
    v.i = ((unsigned int)u) << 16;
    return v.f;
}

__device__ __forceinline__ void bf4add(float4& a, const ushort4& v) {
    a.x += bf2f(v.x); a.y += bf2f(v.y); a.z += bf2f(v.z); a.w += bf2f(v.w);
}

__global__ __launch_bounds__(128) void aggregate_kernel(const ushort4* __restrict__ xh4,
                                                        const int* __restrict__ row_start,
                                                        const unsigned short* __restrict__ csr,
                                                        float4* __restrict__ agg4) {
    __shared__ unsigned short idxs[256];
    __shared__ float4 red[4][32];
    const int node = blockIdx.x;
    const int lane = threadIdx.x & 31;   // features 4*lane .. 4*lane+3
    const int slot = threadIdx.x >> 5;   // edge slot 0..3
    const int start = row_start[node];
    const int end = row_start[node + 1];

    float4 a0 = {0,0,0,0}, a1 = {0,0,0,0}, a2 = {0,0,0,0}, a3 = {0,0,0,0};
    for (int cs = start; cs < end; cs += 256) {
        int m = min(256, end - cs);
        if ((int)threadIdx.x < m) idxs[threadIdx.x] = csr[cs + threadIdx.x];
        if ((int)threadIdx.x + 128 < m) idxs[threadIdx.x + 128] = csr[cs + threadIdx.x + 128];
        __syncthreads();
        int j = slot;
        for (; j + 12 < m; j += 16) {
            int s0 = idxs[j], s1 = idxs[j + 4], s2 = idxs[j + 8], s3 = idxs[j + 12];
            ushort4 v0 = xh4[s0 * 32 + lane];
            ushort4 v1 = xh4[s1 * 32 + lane];
            ushort4 v2 = xh4[s2 * 32 + lane];
            ushort4 v3 = xh4[s3 * 32 + lane];
            bf4add(a0, v0); bf4add(a1, v1); bf4add(a2, v2); bf4add(a3, v3);
        }
        for (; j < m; j += 4) {
            ushort4 v = xh4[(int)idxs[j] * 32 + lane];
            bf4add(a0, v);
        }
        __syncthreads();
    }
    a0.x += a1.x; a0.y += a1.y; a0.z += a1.z; a0.w += a1.w;
    a2.x += a3.x; a2.y += a3.y; a2.z += a3.z; a2.w += a3.w;
    a0.x += a2.x; a0.y += a2.y; a0.z += a2.z; a0.w += a2.w;
    red[slot][lane] = a0;
    __syncthreads();
    if (slot == 0) {
        float4 a = red[0][lane], b = red[1][lane], c = red[2][lane], d = red[3][lane];
        int cntE = end - start;
        float inv = (cntE > 0) ? 1.0f / (float)cntE : 0.0f;
        float4 o;
        o.x = ((a.x + b.x) + (c.x + d.x)) * inv;
        o.y = ((a.y + b.y) + (c.y + d.y)) * inv;
        o.z = ((a.z + b.z) + (c.z + d.z)) * inv;
        o.w = ((a.w + b.w) + (c.w + d.w)) * inv;
        agg4[node * 32 + lane] = o;
    }
}

// ---------------- SAGE linear + residual: 16 nodes/block ----------------

__global__ __launch_bounds__(128) void lin_kernel(const float* __restrict__ x,
                                                  const float* __restrict__ agg,
                                                  const float* __restrict__ Wl,
                                                  const float* __restrict__ bl,
                                                  const float* __restrict__ Wr,
                                                  float* __restrict__ out) {
    __shared__ float xs[16 * D];
    __shared__ float as[16 * D];
    const int f = threadIdx.x;
    const int n0 = blockIdx.x * 16;

    {   // float4 staging: 16*128 = 2048 floats = 512 float4 per array
        const float4* xsrc = (const float4*)(x + n0 * D);
        const float4* asrc = (const float4*)(agg + n0 * D);
        float4* xd = (float4*)xs;
        float4* ad = (float4*)as;
#pragma unroll
        for (int c = 0; c < 4; ++c) {
            xd[c * 128 + f] = xsrc[c * 128 + f];
            ad[c * 128 + f] = asrc[c * 128 + f];
        }
    }
    __syncthreads();

    float bias = bl[f];
    float acc[16];
#pragma unroll
    for (int n = 0; n < 16; ++n) acc[n] = bias;

    const float4* wl4 = (const float4*)(Wl + f * D);
    const float4* wr4 = (const float4*)(Wr + f * D);
    const float4* as4 = (const float4*)as;
    const float4* xs4 = (const float4*)xs;
    for (int kk = 0; kk < 32; ++kk) {
        float4 wl = wl4[kk];
        float4 wr = wr4[kk];
#pragma unroll
        for (int n = 0; n < 16; ++n) {
            float4 a = as4[n * 32 + kk];
            float4 xv = xs4[n * 32 + kk];
            acc[n] += a.x * wl.x + a.y * wl.y + a.z * wl.z + a.w * wl.w;
            acc[n] += xv.x * wr.x + xv.y * wr.y + xv.z * wr.z + xv.w * wr.w;
        }
    }

#pragma unroll
    for (int n = 0; n < 16; ++n) {
        out[(n0 + n) * D + f] = xs[n * D + f] + acc[n];
    }
}

extern "C" void kernel_launch(void* const* d_in, const int* in_sizes, int n_in,
                              void* d_out, int out_size, void* d_ws, size_t ws_size,
                              hipStream_t stream) {
    const float* x  = (const float*)d_in[0];
    const int*   ei = (const int*)d_in[1];     // [2, E] int32
    const float* Wl = (const float*)d_in[2];
    const float* bl = (const float*)d_in[3];
    const float* Wr = (const float*)d_in[4];
    float* out = (float*)d_out;

    // workspace layout (16B-aligned segments)
    unsigned long long* flags = (unsigned long long*)d_ws;               // 64 ULL
    int* row_start = (int*)(flags + 64);                                 // 10016 ints
    unsigned short* cnt   = (unsigned short*)(row_start + 10016);        // NB*N_NODES us
    unsigned short* lrank = cnt + (size_t)NB * N_NODES;                  // N_EDGES us
    unsigned short* csr   = lrank + N_EDGES;                             // N_EDGES us
    unsigned short* xh    = csr + N_EDGES;                               // N_NODES*D us (bf16)
    float* agg = (float*)(xh + (size_t)N_NODES * D);                     // N_NODES*D f32

    cast_kernel<<<(N_NODES * D / 4 + 255) / 256, 256, 0, stream>>>(
        (const float4*)x, (ushort4*)xh);
    hist_local_kernel<<<NB, 1024, 0, stream>>>(ei, lrank, cnt, flags);
    colscan_scan_kernel<<<SB, 256, 0, stream>>>(cnt, row_start, flags);
    scatter_kernel<<<(N_EDGES + 255) / 256, 256, 0, stream>>>(ei, row_start, cnt, lrank, csr);
    aggregate_kernel<<<N_NODES, 128, 0, stream>>>((const ushort4*)xh, row_start, csr,
                                                  (float4*)agg);
    lin_kernel<<<N_NODES / 16, 128, 0, stream>>>(x, agg, Wl, bl, Wr, out);
}

// Round 7
// 146.933 us; speedup vs baseline: 1.0447x; 1.0447x over previous
//
#include <hip/hip_runtime.h>

#define N_NODES 10000
#define D 128
#define N_EDGES 640000
#define NB 128                 // histogram blocks
#define EPB (N_EDGES / NB)     // 5000 edges per block
#define SB 40                  // scan blocks
#define NPSB 250               // nodes per scan block

// ---------------- cast x -> bf16 (so gather working set fits per-XCD L2) -------

__device__ __forceinline__ unsigned short f2bf(float f) {
    union { float f; unsigned int i; } v;
    v.f = f;
    unsigned int b = v.i;
    unsigned int rounded = b + 0x7fffu + ((b >> 16) & 1u);  // RNE
    return (unsigned short)(rounded >> 16);
}

__global__ __launch_bounds__(256) void cast_kernel(const float4* __restrict__ x4,
                                                   ushort4* __restrict__ xh4) {
    int i = blockIdx.x * 256 + threadIdx.x;          // 320000 float4 groups
    if (i < N_NODES * D / 4) {
        float4 v = x4[i];
        ushort4 o;
        o.x = f2bf(v.x);
        o.y = f2bf(v.y);
        o.z = f2bf(v.z);
        o.w = f2bf(v.w);
        xh4[i] = o;
    }
}

// ---------------- pack W into chunk-transposed layout: Wb[c*128+f] = W4[f*32+c] ----

__global__ __launch_bounds__(256) void packw_kernel(const float4* __restrict__ Wl4,
                                                    const float4* __restrict__ Wr4,
                                                    float4* __restrict__ Wbl,
                                                    float4* __restrict__ Wbr) {
    int i = blockIdx.x * 256 + threadIdx.x;          // 4096 entries
    if (i < 32 * 128) {
        int c = i >> 7;
        int f = i & 127;
        Wbl[i] = Wl4[f * 32 + c];
        Wbr[i] = Wr4[f * 32 + c];
    }
}

// ---------------- CSR build: two-level LDS counting sort ----------------

__global__ __launch_bounds__(1024) void hist_local_kernel(const int* __restrict__ ei,
                                                          unsigned short* __restrict__ lrank,
                                                          unsigned short* __restrict__ cnt,
                                                          unsigned long long* __restrict__ flags) {
    __shared__ int h[N_NODES];
    for (int n = threadIdx.x; n < N_NODES; n += 1024) h[n] = 0;
    if (blockIdx.x == 0 && threadIdx.x < SB) flags[threadIdx.x] = 0ULL;
    __syncthreads();
    const int base = blockIdx.x * EPB;
    for (int e = base + threadIdx.x; e < base + EPB; e += 1024) {
        int d = ei[N_EDGES + e];            // row 1 = dst
        lrank[e] = (unsigned short)atomicAdd(&h[d], 1);
    }
    __syncthreads();
    unsigned short* c = cnt + (size_t)blockIdx.x * N_NODES;
    for (int n = threadIdx.x; n < N_NODES; n += 1024) c[n] = (unsigned short)h[n];
}

__global__ __launch_bounds__(256) void colscan_scan_kernel(unsigned short* __restrict__ cnt,
                                                           int* __restrict__ row_start,
                                                           unsigned long long* __restrict__ flags) {
    const int t = threadIdx.x;
    const int b = blockIdx.x;
    const int n = b * NPSB + t;            // valid for t < NPSB
    __shared__ int sc[256];
    __shared__ int blk_excl_sh;

    int deg = 0;
    if (t < NPSB) {
        int s = 0;
#pragma unroll 8
        for (int j = 0; j < NB; ++j) {
            int idx = j * N_NODES + n;
            int v = cnt[idx];
            cnt[idx] = (unsigned short)s;
            s += v;
        }
        deg = s;
    }
    sc[t] = deg;
    __syncthreads();
    for (int off = 1; off < 256; off <<= 1) {
        int v = (t >= off) ? sc[t - off] : 0;
        __syncthreads();
        sc[t] += v;
        __syncthreads();
    }
    const int total = sc[255];
    const int local_excl = sc[t] - deg;

    if (t == 0) {
        int excl = 0;
        if (b == 0) {
            __hip_atomic_store(&flags[0], (2ULL << 32) | (unsigned)total,
                               __ATOMIC_RELEASE, __HIP_MEMORY_SCOPE_AGENT);
        } else {
            __hip_atomic_store(&flags[b], (1ULL << 32) | (unsigned)total,
                               __ATOMIC_RELEASE, __HIP_MEMORY_SCOPE_AGENT);
            int j = b - 1;
            while (j >= 0) {
                unsigned long long f = __hip_atomic_load(&flags[j], __ATOMIC_ACQUIRE,
                                                         __HIP_MEMORY_SCOPE_AGENT);
                unsigned st = (unsigned)(f >> 32);
                if (st == 0) continue;
                excl += (int)(unsigned)(f & 0xffffffffULL);
                if (st == 2) break;
                --j;
            }
            __hip_atomic_store(&flags[b], (2ULL << 32) | (unsigned)(excl + total),
                               __ATOMIC_RELEASE, __HIP_MEMORY_SCOPE_AGENT);
        }
        blk_excl_sh = excl;
    }
    __syncthreads();
    if (t < NPSB) row_start[n] = blk_excl_sh + local_excl;
    if (b == SB - 1 && t == 0) row_start[N_NODES] = N_EDGES;
}

__global__ __launch_bounds__(256) void scatter_kernel(const int* __restrict__ ei,
                                                      const int* __restrict__ row_start,
                                                      const unsigned short* __restrict__ cnt,
                                                      const unsigned short* __restrict__ lrank,
                                                      unsigned short* __restrict__ csr) {
    int i = blockIdx.x * 256 + threadIdx.x;
    if (i < N_EDGES) {
        int b = i / EPB;
        int s = ei[i];
        int d = ei[N_EDGES + i];
        int pos = row_start[d] + (int)cnt[b * N_NODES + d] + (int)lrank[i];
        csr[pos] = (unsigned short)s;
    }
}

// ---------------- mean aggregation: bf16 gather (L2-resident), fp32 accumulate ----

__device__ __forceinline__ float bf2f(unsigned short u) {
    union { unsigned int i; float f; } v;
    v.i = ((unsigned int)u) << 16;
    return v.f;
}

__device__ __forceinline__ void bf4add(float4& a, const ushort4& v) {
    a.x += bf2f(v.x); a.y += bf2f(v.y); a.z += bf2f(v.z); a.w += bf2f(v.w);
}

__global__ __launch_bounds__(128) void aggregate_kernel(const ushort4* __restrict__ xh4,
                                                        const int* __restrict__ row_start,
                                                        const unsigned short* __restrict__ csr,
                                                        float4* __restrict__ agg4) {
    __shared__ unsigned short idxs[256];
    __shared__ float4 red[4][32];
    const int node = blockIdx.x;
    const int lane = threadIdx.x & 31;   // features 4*lane .. 4*lane+3
    const int slot = threadIdx.x >> 5;   // edge slot 0..3
    const int start = row_start[node];
    const int end = row_start[node + 1];

    float4 a0 = {0,0,0,0}, a1 = {0,0,0,0}, a2 = {0,0,0,0}, a3 = {0,0,0,0};
    for (int cs = start; cs < end; cs += 256) {
        int m = min(256, end - cs);
        if ((int)threadIdx.x < m) idxs[threadIdx.x] = csr[cs + threadIdx.x];
        if ((int)threadIdx.x + 128 < m) idxs[threadIdx.x + 128] = csr[cs + threadIdx.x + 128];
        __syncthreads();
        int j = slot;
        for (; j + 12 < m; j += 16) {
            int s0 = idxs[j], s1 = idxs[j + 4], s2 = idxs[j + 8], s3 = idxs[j + 12];
            ushort4 v0 = xh4[s0 * 32 + lane];
            ushort4 v1 = xh4[s1 * 32 + lane];
            ushort4 v2 = xh4[s2 * 32 + lane];
            ushort4 v3 = xh4[s3 * 32 + lane];
            bf4add(a0, v0); bf4add(a1, v1); bf4add(a2, v2); bf4add(a3, v3);
        }
        for (; j < m; j += 4) {
            ushort4 v = xh4[(int)idxs[j] * 32 + lane];
            bf4add(a0, v);
        }
        __syncthreads();
    }
    a0.x += a1.x; a0.y += a1.y; a0.z += a1.z; a0.w += a1.w;
    a2.x += a3.x; a2.y += a3.y; a2.z += a3.z; a2.w += a3.w;
    a0.x += a2.x; a0.y += a2.y; a0.z += a2.z; a0.w += a2.w;
    red[slot][lane] = a0;
    __syncthreads();
    if (slot == 0) {
        float4 a = red[0][lane], b = red[1][lane], c = red[2][lane], d = red[3][lane];
        int cntE = end - start;
        float inv = (cntE > 0) ? 1.0f / (float)cntE : 0.0f;
        float4 o;
        o.x = ((a.x + b.x) + (c.x + d.x)) * inv;
        o.y = ((a.y + b.y) + (c.y + d.y)) * inv;
        o.z = ((a.z + b.z) + (c.z + d.z)) * inv;
        o.w = ((a.w + b.w) + (c.w + d.w)) * inv;
        agg4[node * 32 + lane] = o;
    }
}

// ---------------- SAGE linear + residual ----------------
// 256 threads = (f in [0,128)) x (g in {0,1}); each g-half handles 4 nodes.
// W loads coalesced via packed layout; x/agg rows via wave-uniform scalar loads.

__global__ __launch_bounds__(256) void lin_kernel(const float* __restrict__ x,
                                                  const float* __restrict__ agg,
                                                  const float4* __restrict__ Wbl,
                                                  const float* __restrict__ bl,
                                                  const float4* __restrict__ Wbr,
                                                  float* __restrict__ out) {
    const int f = threadIdx.x & 127;
    const int g = threadIdx.x >> 7;
    const int n0 = blockIdx.x * 8 + g * 4;

    const float bias = bl[f];
    float acc[4] = {bias, bias, bias, bias};

    const float4* arow[4];
    const float4* xrow[4];
#pragma unroll
    for (int n = 0; n < 4; ++n) {
        int ro = __builtin_amdgcn_readfirstlane((n0 + n) * D);
        arow[n] = (const float4*)(agg + ro);
        xrow[n] = (const float4*)(x + ro);
    }

#pragma unroll 8
    for (int c = 0; c < 32; ++c) {
        float4 wl = Wbl[c * 128 + f];
        float4 wr = Wbr[c * 128 + f];
#pragma unroll
        for (int n = 0; n < 4; ++n) {
            float4 a = arow[n][c];
            float4 xv = xrow[n][c];
            acc[n] += a.x * wl.x + a.y * wl.y + a.z * wl.z + a.w * wl.w;
            acc[n] += xv.x * wr.x + xv.y * wr.y + xv.z * wr.z + xv.w * wr.w;
        }
    }

#pragma unroll
    for (int n = 0; n < 4; ++n) {
        out[(n0 + n) * D + f] = x[(n0 + n) * D + f] + acc[n];
    }
}

extern "C" void kernel_launch(void* const* d_in, const int* in_sizes, int n_in,
                              void* d_out, int out_size, void* d_ws, size_t ws_size,
                              hipStream_t stream) {
    const float* x  = (const float*)d_in[0];
    const int*   ei = (const int*)d_in[1];     // [2, E] int32
    const float* Wl = (const float*)d_in[2];
    const float* bl = (const float*)d_in[3];
    const float* Wr = (const float*)d_in[4];
    float* out = (float*)d_out;

    // workspace layout (16B-aligned segments)
    unsigned long long* flags = (unsigned long long*)d_ws;               // 64 ULL
    int* row_start = (int*)(flags + 64);                                 // 10016 ints
    unsigned short* cnt   = (unsigned short*)(row_start + 10016);        // NB*N_NODES us
    unsigned short* lrank = cnt + (size_t)NB * N_NODES;                  // N_EDGES us
    unsigned short* csr   = lrank + N_EDGES;                             // N_EDGES us
    unsigned short* xh    = csr + N_EDGES;                               // N_NODES*D us (bf16)
    float* agg = (float*)(xh + (size_t)N_NODES * D);                     // N_NODES*D f32
    float4* Wbl = (float4*)(agg + (size_t)N_NODES * D);                  // 4096 float4
    float4* Wbr = Wbl + 32 * 128;                                        // 4096 float4

    cast_kernel<<<(N_NODES * D / 4 + 255) / 256, 256, 0, stream>>>(
        (const float4*)x, (ushort4*)xh);
    packw_kernel<<<16, 256, 0, stream>>>((const float4*)Wl, (const float4*)Wr, Wbl, Wbr);
    hist_local_kernel<<<NB, 1024, 0, stream>>>(ei, lrank, cnt, flags);
    colscan_scan_kernel<<<SB, 256, 0, stream>>>(cnt, row_start, flags);
    scatter_kernel<<<(N_EDGES + 255) / 256, 256, 0, stream>>>(ei, row_start, cnt, lrank, csr);
    aggregate_kernel<<<N_NODES, 128, 0, stream>>>((const ushort4*)xh, row_start, csr,
                                                  (float4*)agg);
    lin_kernel<<<N_NODES / 8, 256, 0, stream>>>(x, agg, Wbl, bl, Wbr, out);
}

// Round 8
// 126.225 us; speedup vs baseline: 1.2161x; 1.1641x over previous
//
#include <hip/hip_runtime.h>

#define N_NODES 10000
#define D 128
#define N_EDGES 640000
#define NB 128                 // histogram blocks
#define EPB (N_EDGES / NB)     // 5000 edges per block
#define SB 40                  // scan blocks
#define NPSB 250               // nodes per scan block

typedef __attribute__((ext_vector_type(8))) short bf16x8;   // 8 bf16 = 4 VGPRs
typedef __attribute__((ext_vector_type(4))) float f32x4;    // MFMA accumulator

// ---------------- fp32 -> bf16 (round-to-nearest-even) ----------------

__device__ __forceinline__ unsigned short f2bf(float f) {
    union { float f; unsigned int i; } v;
    v.f = f;
    unsigned int b = v.i;
    unsigned int rounded = b + 0x7fffu + ((b >> 16) & 1u);
    return (unsigned short)(rounded >> 16);
}

__global__ __launch_bounds__(256) void cast_kernel(const float4* __restrict__ x4,
                                                   ushort4* __restrict__ xh4) {
    int i = blockIdx.x * 256 + threadIdx.x;          // 320000 float4 groups
    if (i < N_NODES * D / 4) {
        float4 v = x4[i];
        ushort4 o;
        o.x = f2bf(v.x);
        o.y = f2bf(v.y);
        o.z = f2bf(v.z);
        o.w = f2bf(v.w);
        xh4[i] = o;
    }
}

// cast Wl, Wr to bf16 (keep native row-major [f][k] layout — MFMA B-frag reads it directly)
__global__ __launch_bounds__(256) void castw_kernel(const float* __restrict__ Wl,
                                                    const float* __restrict__ Wr,
                                                    unsigned short* __restrict__ Wlb,
                                                    unsigned short* __restrict__ Wrb) {
    int i = blockIdx.x * 256 + threadIdx.x;          // 16384
    if (i < D * D) {
        Wlb[i] = f2bf(Wl[i]);
        Wrb[i] = f2bf(Wr[i]);
    }
}

// ---------------- CSR build: two-level LDS counting sort ----------------

__global__ __launch_bounds__(1024) void hist_local_kernel(const int* __restrict__ ei,
                                                          unsigned short* __restrict__ lrank,
                                                          unsigned short* __restrict__ cnt,
                                                          unsigned long long* __restrict__ flags) {
    __shared__ int h[N_NODES];
    for (int n = threadIdx.x; n < N_NODES; n += 1024) h[n] = 0;
    if (blockIdx.x == 0 && threadIdx.x < SB) flags[threadIdx.x] = 0ULL;
    __syncthreads();
    const int base = blockIdx.x * EPB;
    for (int e = base + threadIdx.x; e < base + EPB; e += 1024) {
        int d = ei[N_EDGES + e];            // row 1 = dst
        lrank[e] = (unsigned short)atomicAdd(&h[d], 1);
    }
    __syncthreads();
    unsigned short* c = cnt + (size_t)blockIdx.x * N_NODES;
    for (int n = threadIdx.x; n < N_NODES; n += 1024) c[n] = (unsigned short)h[n];
}

__global__ __launch_bounds__(256) void colscan_scan_kernel(unsigned short* __restrict__ cnt,
                                                           int* __restrict__ row_start,
                                                           unsigned long long* __restrict__ flags) {
    const int t = threadIdx.x;
    const int b = blockIdx.x;
    const int n = b * NPSB + t;            // valid for t < NPSB
    __shared__ int sc[256];
    __shared__ int blk_excl_sh;

    int deg = 0;
    if (t < NPSB) {
        int s = 0;
#pragma unroll 8
        for (int j = 0; j < NB; ++j) {
            int idx = j * N_NODES + n;
            int v = cnt[idx];
            cnt[idx] = (unsigned short)s;
            s += v;
        }
        deg = s;
    }
    sc[t] = deg;
    __syncthreads();
    for (int off = 1; off < 256; off <<= 1) {
        int v = (t >= off) ? sc[t - off] : 0;
        __syncthreads();
        sc[t] += v;
        __syncthreads();
    }
    const int total = sc[255];
    const int local_excl = sc[t] - deg;

    if (t == 0) {
        int excl = 0;
        if (b == 0) {
            __hip_atomic_store(&flags[0], (2ULL << 32) | (unsigned)total,
                               __ATOMIC_RELEASE, __HIP_MEMORY_SCOPE_AGENT);
        } else {
            __hip_atomic_store(&flags[b], (1ULL << 32) | (unsigned)total,
                               __ATOMIC_RELEASE, __HIP_MEMORY_SCOPE_AGENT);
            int j = b - 1;
            while (j >= 0) {
                unsigned long long f = __hip_atomic_load(&flags[j], __ATOMIC_ACQUIRE,
                                                         __HIP_MEMORY_SCOPE_AGENT);
                unsigned st = (unsigned)(f >> 32);
                if (st == 0) continue;
                excl += (int)(unsigned)(f & 0xffffffffULL);
                if (st == 2) break;
                --j;
            }
            __hip_atomic_store(&flags[b], (2ULL << 32) | (unsigned)(excl + total),
                               __ATOMIC_RELEASE, __HIP_MEMORY_SCOPE_AGENT);
        }
        blk_excl_sh = excl;
    }
    __syncthreads();
    if (t < NPSB) row_start[n] = blk_excl_sh + local_excl;
    if (b == SB - 1 && t == 0) row_start[N_NODES] = N_EDGES;
}

__global__ __launch_bounds__(256) void scatter_kernel(const int* __restrict__ ei,
                                                      const int* __restrict__ row_start,
                                                      const unsigned short* __restrict__ cnt,
                                                      const unsigned short* __restrict__ lrank,
                                                      unsigned short* __restrict__ csr) {
    int i = blockIdx.x * 256 + threadIdx.x;
    if (i < N_EDGES) {
        int b = i / EPB;
        int s = ei[i];
        int d = ei[N_EDGES + i];
        int pos = row_start[d] + (int)cnt[b * N_NODES + d] + (int)lrank[i];
        csr[pos] = (unsigned short)s;
    }
}

// ---------------- mean aggregation: bf16 gather, fp32 accumulate, bf16 out ----------

__device__ __forceinline__ float bf2f(unsigned short u) {
    union { unsigned int i; float f; } v;
    v.i = ((unsigned int)u) << 16;
    return v.f;
}

__device__ __forceinline__ void bf4add(float4& a, const ushort4& v) {
    a.x += bf2f(v.x); a.y += bf2f(v.y); a.z += bf2f(v.z); a.w += bf2f(v.w);
}

__global__ __launch_bounds__(128) void aggregate_kernel(const ushort4* __restrict__ xh4,
                                                        const int* __restrict__ row_start,
                                                        const unsigned short* __restrict__ csr,
                                                        ushort4* __restrict__ aggb4) {
    __shared__ unsigned short idxs[256];
    __shared__ float4 red[4][32];
    const int node = blockIdx.x;
    const int lane = threadIdx.x & 31;   // features 4*lane .. 4*lane+3
    const int slot = threadIdx.x >> 5;   // edge slot 0..3
    const int start = row_start[node];
    const int end = row_start[node + 1];

    float4 a0 = {0,0,0,0}, a1 = {0,0,0,0}, a2 = {0,0,0,0}, a3 = {0,0,0,0};
    for (int cs = start; cs < end; cs += 256) {
        int m = min(256, end - cs);
        if ((int)threadIdx.x < m) idxs[threadIdx.x] = csr[cs + threadIdx.x];
        if ((int)threadIdx.x + 128 < m) idxs[threadIdx.x + 128] = csr[cs + threadIdx.x + 128];
        __syncthreads();
        int j = slot;
        for (; j + 12 < m; j += 16) {
            int s0 = idxs[j], s1 = idxs[j + 4], s2 = idxs[j + 8], s3 = idxs[j + 12];
            ushort4 v0 = xh4[s0 * 32 + lane];
            ushort4 v1 = xh4[s1 * 32 + lane];
            ushort4 v2 = xh4[s2 * 32 + lane];
            ushort4 v3 = xh4[s3 * 32 + lane];
            bf4add(a0, v0); bf4add(a1, v1); bf4add(a2, v2); bf4add(a3, v3);
        }
        for (; j < m; j += 4) {
            ushort4 v = xh4[(int)idxs[j] * 32 + lane];
            bf4add(a0, v);
        }
        __syncthreads();
    }
    a0.x += a1.x; a0.y += a1.y; a0.z += a1.z; a0.w += a1.w;
    a2.x += a3.x; a2.y += a3.y; a2.z += a3.z; a2.w += a3.w;
    a0.x += a2.x; a0.y += a2.y; a0.z += a2.z; a0.w += a2.w;
    red[slot][lane] = a0;
    __syncthreads();
    if (slot == 0) {
        float4 a = red[0][lane], b = red[1][lane], c = red[2][lane], d = red[3][lane];
        int cntE = end - start;
        float inv = (cntE > 0) ? 1.0f / (float)cntE : 0.0f;
        ushort4 o;
        o.x = f2bf(((a.x + b.x) + (c.x + d.x)) * inv);
        o.y = f2bf(((a.y + b.y) + (c.y + d.y)) * inv);
        o.z = f2bf(((a.z + b.z) + (c.z + d.z)) * inv);
        o.w = f2bf(((a.w + b.w) + (c.w + d.w)) * inv);
        aggb4[node * 32 + lane] = o;
    }
}

// ---------------- SAGE linear + residual via bf16 MFMA ----------------
// out[m][f] = x[m][f] + bl[f] + sum_k aggb[m][k]*Wlb[f][k] + sum_k xh[m][k]*Wrb[f][k]
// One wave per 16x16 C tile; K=256 as 8 chained mfma_f32_16x16x32_bf16.
// A-frag: A[m=lane&15][k=quad*8+j]; B-frag: B[k=quad*8+j][n=lane&15] = W[n][k] row-major;
// C/D: col=lane&15, row=quad*4+reg  (verified mappings, m89/m120).

__global__ __launch_bounds__(256) void lin_mfma_kernel(const float* __restrict__ x,
                                                       const unsigned short* __restrict__ aggb,
                                                       const unsigned short* __restrict__ xh,
                                                       const unsigned short* __restrict__ Wlb,
                                                       const unsigned short* __restrict__ Wrb,
                                                       const float* __restrict__ bl,
                                                       float* __restrict__ out) {
    const int wave = threadIdx.x >> 6;
    const int lane = threadIdx.x & 63;
    const int l15 = lane & 15;
    const int quad = lane >> 4;
    const int mt = blockIdx.x * 4 + wave;            // M-tile 0..624 (10000 = 625*16)
    if (mt >= 625) return;
    const int row0 = mt * 16;
    const int out0 = blockIdx.y * 16;

    const int m = row0 + l15;                        // A row this lane loads
    const int f = out0 + l15;                        // output feature = B row = C col

    const bf16x8* arow = (const bf16x8*)(aggb + (size_t)m * D) + quad;   // +8 elems per quad
    const bf16x8* xrow = (const bf16x8*)(xh   + (size_t)m * D) + quad;
    const bf16x8* wlro = (const bf16x8*)(Wlb + (size_t)f * D) + quad;
    const bf16x8* wrro = (const bf16x8*)(Wrb + (size_t)f * D) + quad;

    f32x4 c = {0.f, 0.f, 0.f, 0.f};
#pragma unroll
    for (int kk = 0; kk < 4; ++kk) {                 // k0 = kk*32
        c = __builtin_amdgcn_mfma_f32_16x16x32_bf16(arow[kk * 4], wlro[kk * 4], c, 0, 0, 0);
        c = __builtin_amdgcn_mfma_f32_16x16x32_bf16(xrow[kk * 4], wrro[kk * 4], c, 0, 0, 0);
    }

    const float bias = bl[f];
#pragma unroll
    for (int r = 0; r < 4; ++r) {
        int row = row0 + quad * 4 + r;
        int idx = row * D + f;
        out[idx] = x[idx] + bias + c[r];
    }
}

extern "C" void kernel_launch(void* const* d_in, const int* in_sizes, int n_in,
                              void* d_out, int out_size, void* d_ws, size_t ws_size,
                              hipStream_t stream) {
    const float* x  = (const float*)d_in[0];
    const int*   ei = (const int*)d_in[1];     // [2, E] int32
    const float* Wl = (const float*)d_in[2];
    const float* bl = (const float*)d_in[3];
    const float* Wr = (const float*)d_in[4];
    float* out = (float*)d_out;

    // workspace layout (16B-aligned segments)
    unsigned long long* flags = (unsigned long long*)d_ws;               // 64 ULL
    int* row_start = (int*)(flags + 64);                                 // 10016 ints
    unsigned short* cnt   = (unsigned short*)(row_start + 10016);        // NB*N_NODES us
    unsigned short* lrank = cnt + (size_t)NB * N_NODES;                  // N_EDGES us
    unsigned short* csr   = lrank + N_EDGES;                             // N_EDGES us
    unsigned short* xh    = csr + N_EDGES;                               // N_NODES*D (bf16)
    unsigned short* aggb  = xh + (size_t)N_NODES * D;                    // N_NODES*D (bf16)
    unsigned short* Wlb   = aggb + (size_t)N_NODES * D;                  // D*D (bf16)
    unsigned short* Wrb   = Wlb + D * D;                                 // D*D (bf16)

    cast_kernel<<<(N_NODES * D / 4 + 255) / 256, 256, 0, stream>>>(
        (const float4*)x, (ushort4*)xh);
    castw_kernel<<<(D * D + 255) / 256, 256, 0, stream>>>(Wl, Wr, Wlb, Wrb);
    hist_local_kernel<<<NB, 1024, 0, stream>>>(ei, lrank, cnt, flags);
    colscan_scan_kernel<<<SB, 256, 0, stream>>>(cnt, row_start, flags);
    scatter_kernel<<<(N_EDGES + 255) / 256, 256, 0, stream>>>(ei, row_start, cnt, lrank, csr);
    aggregate_kernel<<<N_NODES, 128, 0, stream>>>((const ushort4*)xh, row_start, csr,
                                                  (ushort4*)aggb);
    lin_mfma_kernel<<<dim3(157, 8), 256, 0, stream>>>(x, aggb, xh, Wlb, Wrb, bl, out);
}

// Round 9
// 121.501 us; speedup vs baseline: 1.2633x; 1.0389x over previous
//
#include <hip/hip_runtime.h>

#define N_NODES 10000
#define D 128
#define N_EDGES 640000
#define NB 128                 // histogram blocks
#define EPB (N_EDGES / NB)     // 5000 edges per block
#define SB 40                  // scan blocks
#define NPSB 250               // nodes per scan block

typedef __attribute__((ext_vector_type(8))) short bf16x8;          // MFMA A/B frag
typedef __attribute__((ext_vector_type(4))) float f32x4;           // MFMA acc
typedef __attribute__((ext_vector_type(8))) unsigned short us8;    // 16B bf16 row chunk
typedef __attribute__((ext_vector_type(8))) float f32x8;

// ---------------- fp32 -> bf16 (round-to-nearest-even) ----------------

__device__ __forceinline__ unsigned short f2bf(float f) {
    union { float f; unsigned int i; } v;
    v.f = f;
    unsigned int b = v.i;
    unsigned int rounded = b + 0x7fffu + ((b >> 16) & 1u);
    return (unsigned short)(rounded >> 16);
}

__device__ __forceinline__ float bf2f(unsigned short u) {
    union { unsigned int i; float f; } v;
    v.i = ((unsigned int)u) << 16;
    return v.f;
}

__device__ __forceinline__ f32x8 bf2f8(us8 v) {
    f32x8 r;
#pragma unroll
    for (int t = 0; t < 8; ++t) r[t] = bf2f(v[t]);
    return r;
}

// ---------------- fused: cast x->bf16, cast W->bf16, LDS histogram ----------------

__global__ __launch_bounds__(1024) void hist_cast_kernel(const int* __restrict__ ei,
                                                         const float4* __restrict__ x4,
                                                         const float4* __restrict__ Wl4,
                                                         const float4* __restrict__ Wr4,
                                                         ushort4* __restrict__ xh4,
                                                         ushort4* __restrict__ Wlb4,
                                                         ushort4* __restrict__ Wrb4,
                                                         unsigned short* __restrict__ lrank,
                                                         unsigned short* __restrict__ cnt,
                                                         unsigned long long* __restrict__ flags) {
    __shared__ int h[N_NODES];
    for (int n = threadIdx.x; n < N_NODES; n += 1024) h[n] = 0;
    if (blockIdx.x == 0 && threadIdx.x < SB) flags[threadIdx.x] = 0ULL;

    // cast x (320000 float4 groups) + W (4096 float4 groups) across the whole grid
    const int gid = blockIdx.x * 1024 + threadIdx.x;      // 131072 threads
    for (int i = gid; i < N_NODES * D / 4; i += NB * 1024) {
        float4 v = x4[i];
        ushort4 o;
        o.x = f2bf(v.x); o.y = f2bf(v.y); o.z = f2bf(v.z); o.w = f2bf(v.w);
        xh4[i] = o;
    }
    if (gid < D * D / 4) {
        float4 a = Wl4[gid], b = Wr4[gid];
        ushort4 oa, ob;
        oa.x = f2bf(a.x); oa.y = f2bf(a.y); oa.z = f2bf(a.z); oa.w = f2bf(a.w);
        ob.x = f2bf(b.x); ob.y = f2bf(b.y); ob.z = f2bf(b.z); ob.w = f2bf(b.w);
        Wlb4[gid] = oa;
        Wrb4[gid] = ob;
    }
    __syncthreads();

    const int base = blockIdx.x * EPB;
    for (int e = base + threadIdx.x; e < base + EPB; e += 1024) {
        int d = ei[N_EDGES + e];            // row 1 = dst
        lrank[e] = (unsigned short)atomicAdd(&h[d], 1);
    }
    __syncthreads();
    unsigned short* c = cnt + (size_t)blockIdx.x * N_NODES;
    for (int n = threadIdx.x; n < N_NODES; n += 1024) c[n] = (unsigned short)h[n];
}

// ---------------- fused column scan + node scan (decoupled lookback) ----------------

__global__ __launch_bounds__(256) void colscan_scan_kernel(unsigned short* __restrict__ cnt,
                                                           int* __restrict__ row_start,
                                                           unsigned long long* __restrict__ flags) {
    const int t = threadIdx.x;
    const int b = blockIdx.x;
    const int n = b * NPSB + t;            // valid for t < NPSB
    __shared__ int sc[256];
    __shared__ int blk_excl_sh;

    int deg = 0;
    if (t < NPSB) {
        int s = 0;
#pragma unroll 8
        for (int j = 0; j < NB; ++j) {
            int idx = j * N_NODES + n;
            int v = cnt[idx];
            cnt[idx] = (unsigned short)s;
            s += v;
        }
        deg = s;
    }
    sc[t] = deg;
    __syncthreads();
    for (int off = 1; off < 256; off <<= 1) {
        int v = (t >= off) ? sc[t - off] : 0;
        __syncthreads();
        sc[t] += v;
        __syncthreads();
    }
    const int total = sc[255];
    const int local_excl = sc[t] - deg;

    if (t == 0) {
        int excl = 0;
        if (b == 0) {
            __hip_atomic_store(&flags[0], (2ULL << 32) | (unsigned)total,
                               __ATOMIC_RELEASE, __HIP_MEMORY_SCOPE_AGENT);
        } else {
            __hip_atomic_store(&flags[b], (1ULL << 32) | (unsigned)total,
                               __ATOMIC_RELEASE, __HIP_MEMORY_SCOPE_AGENT);
            int j = b - 1;
            while (j >= 0) {
                unsigned long long f = __hip_atomic_load(&flags[j], __ATOMIC_ACQUIRE,
                                                         __HIP_MEMORY_SCOPE_AGENT);
                unsigned st = (unsigned)(f >> 32);
                if (st == 0) continue;
                excl += (int)(unsigned)(f & 0xffffffffULL);
                if (st == 2) break;
                --j;
            }
            __hip_atomic_store(&flags[b], (2ULL << 32) | (unsigned)(excl + total),
                               __ATOMIC_RELEASE, __HIP_MEMORY_SCOPE_AGENT);
        }
        blk_excl_sh = excl;
    }
    __syncthreads();
    if (t < NPSB) row_start[n] = blk_excl_sh + local_excl;
    if (b == SB - 1 && t == 0) row_start[N_NODES] = N_EDGES;
}

__global__ __launch_bounds__(256) void scatter_kernel(const int* __restrict__ ei,
                                                      const int* __restrict__ row_start,
                                                      const unsigned short* __restrict__ cnt,
                                                      const unsigned short* __restrict__ lrank,
                                                      unsigned short* __restrict__ csr) {
    int i = blockIdx.x * 256 + threadIdx.x;
    if (i < N_EDGES) {
        int b = i / EPB;
        int s = ei[i];
        int d = ei[N_EDGES + i];
        int pos = row_start[d] + (int)cnt[b * N_NODES + d] + (int)lrank[i];
        csr[pos] = (unsigned short)s;
    }
}

// ---------------- mean aggregation: 16B gather lanes, 8 slots, 4-deep ILP ----------
// block = 128 threads: lane16 = feature octet (16 x 8 = 128 features), slot = 0..7.

__global__ __launch_bounds__(128) void aggregate_kernel(const us8* __restrict__ xh8,
                                                        const int* __restrict__ row_start,
                                                        const unsigned short* __restrict__ csr,
                                                        us8* __restrict__ aggb8) {
    __shared__ unsigned short idxs[256];
    __shared__ f32x8 red[8][16];
    const int node = blockIdx.x;
    const int lane16 = threadIdx.x & 15;   // feature octet
    const int slot = threadIdx.x >> 4;     // edge slot 0..7
    const int start = row_start[node];
    const int end = row_start[node + 1];

    f32x8 a0 = 0.f, a1 = 0.f, a2 = 0.f, a3 = 0.f;
    for (int cs = start; cs < end; cs += 256) {
        int m = min(256, end - cs);
        if ((int)threadIdx.x < m) idxs[threadIdx.x] = csr[cs + threadIdx.x];
        if ((int)threadIdx.x + 128 < m) idxs[threadIdx.x + 128] = csr[cs + threadIdx.x + 128];
        __syncthreads();
        int j = slot;
        for (; j + 24 < m; j += 32) {
            int s0 = idxs[j], s1 = idxs[j + 8], s2 = idxs[j + 16], s3 = idxs[j + 24];
            us8 v0 = xh8[s0 * 16 + lane16];
            us8 v1 = xh8[s1 * 16 + lane16];
            us8 v2 = xh8[s2 * 16 + lane16];
            us8 v3 = xh8[s3 * 16 + lane16];
            a0 += bf2f8(v0); a1 += bf2f8(v1); a2 += bf2f8(v2); a3 += bf2f8(v3);
        }
        for (; j < m; j += 8) {
            us8 v = xh8[(int)idxs[j] * 16 + lane16];
            a0 += bf2f8(v);
        }
        __syncthreads();
    }
    a0 = (a0 + a1) + (a2 + a3);
    red[slot][lane16] = a0;
    __syncthreads();
    if (slot == 0) {
        f32x8 o = red[0][lane16];
#pragma unroll
        for (int s = 1; s < 8; ++s) o += red[s][lane16];
        int cntE = end - start;
        float inv = (cntE > 0) ? 1.0f / (float)cntE : 0.0f;
        us8 pack;
#pragma unroll
        for (int t = 0; t < 8; ++t) pack[t] = f2bf(o[t] * inv);
        aggb8[node * 16 + lane16] = pack;
    }
}

// ---------------- SAGE linear + residual via bf16 MFMA ----------------
// One wave per 16x16 C tile; K=256 as 8 chained mfma_f32_16x16x32_bf16.

__global__ __launch_bounds__(256) void lin_mfma_kernel(const float* __restrict__ x,
                                                       const unsigned short* __restrict__ aggb,
                                                       const unsigned short* __restrict__ xh,
                                                       const unsigned short* __restrict__ Wlb,
                                                       const unsigned short* __restrict__ Wrb,
                                                       const float* __restrict__ bl,
                                                       float* __restrict__ out) {
    const int wave = threadIdx.x >> 6;
    const int lane = threadIdx.x & 63;
    const int l15 = lane & 15;
    const int quad = lane >> 4;
    const int mt = blockIdx.x * 4 + wave;            // M-tile 0..624 (10000 = 625*16)
    if (mt >= 625) return;
    const int row0 = mt * 16;
    const int out0 = blockIdx.y * 16;

    const int m = row0 + l15;
    const int f = out0 + l15;

    const bf16x8* arow = (const bf16x8*)(aggb + (size_t)m * D) + quad;
    const bf16x8* xrow = (const bf16x8*)(xh   + (size_t)m * D) + quad;
    const bf16x8* wlro = (const bf16x8*)(Wlb + (size_t)f * D) + quad;
    const bf16x8* wrro = (const bf16x8*)(Wrb + (size_t)f * D) + quad;

    f32x4 c = {0.f, 0.f, 0.f, 0.f};
#pragma unroll
    for (int kk = 0; kk < 4; ++kk) {
        c = __builtin_amdgcn_mfma_f32_16x16x32_bf16(arow[kk * 4], wlro[kk * 4], c, 0, 0, 0);
        c = __builtin_amdgcn_mfma_f32_16x16x32_bf16(xrow[kk * 4], wrro[kk * 4], c, 0, 0, 0);
    }

    const float bias = bl[f];
#pragma unroll
    for (int r = 0; r < 4; ++r) {
        int row = row0 + quad * 4 + r;
        int idx = row * D + f;
        out[idx] = x[idx] + bias + c[r];
    }
}

extern "C" void kernel_launch(void* const* d_in, const int* in_sizes, int n_in,
                              void* d_out, int out_size, void* d_ws, size_t ws_size,
                              hipStream_t stream) {
    const float* x  = (const float*)d_in[0];
    const int*   ei = (const int*)d_in[1];     // [2, E] int32
    const float* Wl = (const float*)d_in[2];
    const float* bl = (const float*)d_in[3];
    const float* Wr = (const float*)d_in[4];
    float* out = (float*)d_out;

    // workspace layout (16B-aligned segments)
    unsigned long long* flags = (unsigned long long*)d_ws;               // 64 ULL
    int* row_start = (int*)(flags + 64);                                 // 10016 ints
    unsigned short* cnt   = (unsigned short*)(row_start + 10016);        // NB*N_NODES us
    unsigned short* lrank = cnt + (size_t)NB * N_NODES;                  // N_EDGES us
    unsigned short* csr   = lrank + N_EDGES;                             // N_EDGES us
    unsigned short* xh    = csr + N_EDGES;                               // N_NODES*D (bf16)
    unsigned short* aggb  = xh + (size_t)N_NODES * D;                    // N_NODES*D (bf16)
    unsigned short* Wlb   = aggb + (size_t)N_NODES * D;                  // D*D (bf16)
    unsigned short* Wrb   = Wlb + D * D;                                 // D*D (bf16)

    hist_cast_kernel<<<NB, 1024, 0, stream>>>(ei, (const float4*)x, (const float4*)Wl,
                                              (const float4*)Wr, (ushort4*)xh,
                                              (ushort4*)Wlb, (ushort4*)Wrb,
                                              lrank, cnt, flags);
    colscan_scan_kernel<<<SB, 256, 0, stream>>>(cnt, row_start, flags);
    scatter_kernel<<<(N_EDGES + 255) / 256, 256, 0, stream>>>(ei, row_start, cnt, lrank, csr);
    aggregate_kernel<<<N_NODES, 128, 0, stream>>>((const us8*)xh, row_start, csr,
                                                  (us8*)aggb);
    lin_mfma_kernel<<<dim3(157, 8), 256, 0, stream>>>(x, aggb, xh, Wlb, Wrb, bl, out);
}